// Round 2
// baseline (97.191 us; speedup 1.0000x reference)
//
#include <hip/hip_runtime.h>

namespace {
constexpr int NP  = 28;
constexpr int PTS = 262144;
constexpr int FPN = PTS * 3;            // floats per n-slice = 786432
constexpr int BPN = 256;                // chunks per (array, n): 256chunks*256thr*12f = 786432
constexpr int NCHUNK = 2 * NP * BPN;    // 14336
constexpr int GRID   = 2048;            // 7 chunks per block
constexpr long long DOF6_OFF = 2LL * NP * FPN;  // 44040192
typedef float v4 __attribute__((ext_vector_type(4)));
}

// Build R (row-major 3x3) and b = t + C - C@R for slice n.
// Matches reference: R = Rx@Ry@Rz; M = T(-C)@Rot(R)@T(t)@T(C); p' = p@R + b.
__device__ __forceinline__ void euler_Rb(const float* __restrict__ C,
                                         const float* __restrict__ ang,
                                         const float* __restrict__ t,
                                         int n, float R[9], float b[3]) {
    float ax = ang[n*3+0], ay = ang[n*3+1], az = ang[n*3+2];
    float cx = cosf(ax), sx = sinf(ax);
    float cy = cosf(ay), sy = sinf(ay);
    float cz = cosf(az), sz = sinf(az);
    // A = Rx@Ry
    float A00 = cy,       A01 = 0.f, A02 = sy;
    float A10 = sx*sy,    A11 = cx,  A12 = -sx*cy;
    float A20 = -cx*sy,   A21 = sx,  A22 = cx*cy;
    // R = A@Rz ; Rz = [[cz,-sz,0],[sz,cz,0],[0,0,1]]
    R[0] = A00*cz + A01*sz;  R[1] = -A00*sz + A01*cz;  R[2] = A02;
    R[3] = A10*cz + A11*sz;  R[4] = -A10*sz + A11*cz;  R[5] = A12;
    R[6] = A20*cz + A21*sz;  R[7] = -A20*sz + A21*cz;  R[8] = A22;
    float C0 = C[n*3+0], C1 = C[n*3+1], C2 = C[n*3+2];
    b[0] = t[n*3+0] + C0 - (C0*R[0] + C1*R[3] + C2*R[6]);
    b[1] = t[n*3+1] + C1 - (C0*R[1] + C1*R[4] + C2*R[7]);
    b[2] = t[n*3+2] + C2 - (C0*R[2] + C1*R[5] + C2*R[8]);
}

// One tiny block: threads 0..55 write the 56 [R|b] matrices to ws;
// threads 0..27 also compute dof6 straight into out.
__global__ void setup_kernel(const float* __restrict__ C,
                             const float* __restrict__ ang1,
                             const float* __restrict__ ang2,
                             const float* __restrict__ t1,
                             const float* __restrict__ t2,
                             float* __restrict__ mats,
                             float* __restrict__ out) {
    int tid = threadIdx.x;
    if (tid < 2 * NP) {
        int arr = tid / NP;
        int n   = tid - arr * NP;
        float R[9], b[3];
        euler_Rb(C, arr ? ang2 : ang1, arr ? t2 : t1, n, R, b);
        float* m = mats + tid * 12;
        #pragma unroll
        for (int i = 0; i < 9; ++i) m[i] = R[i];
        m[9] = b[0]; m[10] = b[1]; m[11] = b[2];
    }
    if (tid < NP) {
        int n = tid;
        float R1[9], b1v[3], R2[9], b2v[3];
        euler_Rb(C, ang1, t1, n, R1, b1v);
        euler_Rb(C, ang2, t2, n, R2, b2v);
        // Ffinal = inv(M1)@M2: Rf = R1^T @ R2, tf = b2 - b1@Rf
        float Rf[9];
        #pragma unroll
        for (int i = 0; i < 3; ++i)
            #pragma unroll
            for (int j = 0; j < 3; ++j)
                Rf[3*i+j] = R1[0+i]*R2[0+j] + R1[3+i]*R2[3+j] + R1[6+i]*R2[6+j];
        float tf0 = b2v[0] - (b1v[0]*Rf[0] + b1v[1]*Rf[3] + b1v[2]*Rf[6]);
        float tf1 = b2v[1] - (b1v[0]*Rf[1] + b1v[1]*Rf[4] + b1v[2]*Rf[7]);
        float tf2 = b2v[2] - (b1v[0]*Rf[2] + b1v[1]*Rf[5] + b1v[2]*Rf[8]);
        // se3_log
        const float eps = 1e-4f, cos_bound = 1e-4f;
        float tr = Rf[0] + Rf[4] + Rf[8];
        float cc = (tr - 1.f) * 0.5f;
        cc = fminf(fmaxf(cc, -1.f + cos_bound), 1.f - cos_bound);
        float phi = acosf(cc);
        float sp  = sinf(phi);
        float fac = (fabsf(sp) > 0.5f * eps) ? (phi / (2.f * sp))
                                             : (0.5f + phi * phi * (1.f/12.f));
        float w0 = fac * (Rf[7] - Rf[5]);
        float w1 = fac * (Rf[2] - Rf[6]);
        float w2 = fac * (Rf[3] - Rf[1]);
        float ww  = w0*w0 + w1*w1 + w2*w2;
        float th2 = fmaxf(ww, eps);
        float th  = sqrtf(th2);
        float a  = (1.f - cosf(th)) / th2;
        float bb = (th - sinf(th)) / (th2 * th);
        float V00 = 1.f + bb*(w0*w0 - ww);
        float V01 = -a*w2 + bb*w0*w1;
        float V02 =  a*w1 + bb*w0*w2;
        float V10 =  a*w2 + bb*w0*w1;
        float V11 = 1.f + bb*(w1*w1 - ww);
        float V12 = -a*w0 + bb*w1*w2;
        float V20 = -a*w1 + bb*w0*w2;
        float V21 =  a*w0 + bb*w1*w2;
        float V22 = 1.f + bb*(w2*w2 - ww);
        float a00 = V11*V22 - V12*V21;
        float a01 = V02*V21 - V01*V22;
        float a02 = V01*V12 - V02*V11;
        float a10 = V12*V20 - V10*V22;
        float a11 = V00*V22 - V02*V20;
        float a12 = V02*V10 - V00*V12;
        float a20 = V10*V21 - V11*V20;
        float a21 = V01*V20 - V00*V21;
        float a22 = V00*V11 - V01*V10;
        float det = V00*a00 + V01*a10 + V02*a20;
        float inv = 1.f / det;
        float x0 = (a00*tf0 + a01*tf1 + a02*tf2) * inv;
        float x1 = (a10*tf0 + a11*tf1 + a12*tf2) * inv;
        float x2 = (a20*tf0 + a21*tf1 + a22*tf2) * inv;
        float* d = out + DOF6_OFF + (long long)n * 6;
        d[0] = x0; d[1] = x1; d[2] = x2;
        d[3] = w0; d[4] = w1; d[5] = w2;
    }
}

__global__ __launch_bounds__(256) void transform_kernel(
        const float* __restrict__ Xv, const float* __restrict__ tXv,
        const float* __restrict__ mats, float* __restrict__ out) {
    const int tid = threadIdx.x;
    for (int c = blockIdx.x; c < NCHUNK; c += GRID) {
        int arr = (c >= NP * BPN) ? 1 : 0;
        int w   = c - arr * (NP * BPN);
        int n   = w >> 8;
        int blk = w & 255;
        const float* __restrict__ m = mats + (arr * NP + n) * 12;
        // broadcast loads (uniform address -> one cache line, L1 hit)
        const float R00=m[0],R01=m[1],R02=m[2],R10=m[3],R11=m[4],R12=m[5],
                    R20=m[6],R21=m[7],R22=m[8],b0=m[9],b1=m[10],b2=m[11];
        const float* __restrict__ in = arr ? tXv : Xv;
        float* __restrict__ o = out + (long long)arr * (long long)NP * FPN;
        long long base = (long long)n * FPN + (long long)(blk * 256 + tid) * 12;
        v4 v0 = __builtin_nontemporal_load((const v4*)(in + base));
        v4 v1 = __builtin_nontemporal_load((const v4*)(in + base + 4));
        v4 v2 = __builtin_nontemporal_load((const v4*)(in + base + 8));
        v4 r0, r1, r2;
        float px, py, pz;
        px=v0.x; py=v0.y; pz=v0.z;
        r0.x = fmaf(px,R00,fmaf(py,R10,fmaf(pz,R20,b0)));
        r0.y = fmaf(px,R01,fmaf(py,R11,fmaf(pz,R21,b1)));
        r0.z = fmaf(px,R02,fmaf(py,R12,fmaf(pz,R22,b2)));
        px=v0.w; py=v1.x; pz=v1.y;
        r0.w = fmaf(px,R00,fmaf(py,R10,fmaf(pz,R20,b0)));
        r1.x = fmaf(px,R01,fmaf(py,R11,fmaf(pz,R21,b1)));
        r1.y = fmaf(px,R02,fmaf(py,R12,fmaf(pz,R22,b2)));
        px=v1.z; py=v1.w; pz=v2.x;
        r1.z = fmaf(px,R00,fmaf(py,R10,fmaf(pz,R20,b0)));
        r1.w = fmaf(px,R01,fmaf(py,R11,fmaf(pz,R21,b1)));
        r2.x = fmaf(px,R02,fmaf(py,R12,fmaf(pz,R22,b2)));
        px=v2.y; py=v2.z; pz=v2.w;
        r2.y = fmaf(px,R00,fmaf(py,R10,fmaf(pz,R20,b0)));
        r2.z = fmaf(px,R01,fmaf(py,R11,fmaf(pz,R21,b1)));
        r2.w = fmaf(px,R02,fmaf(py,R12,fmaf(pz,R22,b2)));
        __builtin_nontemporal_store(r0, (v4*)(o + base));
        __builtin_nontemporal_store(r1, (v4*)(o + base + 4));
        __builtin_nontemporal_store(r2, (v4*)(o + base + 8));
    }
}

extern "C" void kernel_launch(void* const* d_in, const int* in_sizes, int n_in,
                              void* d_out, int out_size, void* d_ws, size_t ws_size,
                              hipStream_t stream) {
    const float* C   = (const float*)d_in[0];
    const float* Xv  = (const float*)d_in[1];
    const float* tXv = (const float*)d_in[2];
    const float* a1  = (const float*)d_in[3];
    const float* a2  = (const float*)d_in[4];
    const float* t1  = (const float*)d_in[5];
    const float* t2  = (const float*)d_in[6];
    float* mats = (float*)d_ws;   // 56 * 12 floats = 2688 B
    float* out  = (float*)d_out;
    setup_kernel<<<1, 64, 0, stream>>>(C, a1, a2, t1, t2, mats, out);
    transform_kernel<<<GRID, 256, 0, stream>>>(Xv, tXv, mats, out);
}

// Round 3
// 66.829 us; speedup vs baseline: 1.4543x; 1.4543x over previous
//
#include <hip/hip_runtime.h>

namespace {
constexpr int NP  = 28;
constexpr int PTS = 262144;
constexpr int FPN = PTS * 3;            // floats per n-slice = 786432
constexpr int CHUNK_F = 3072;           // floats per block = 256 thr * 12
constexpr int BPN = FPN / CHUNK_F;      // 256 chunks per (array,n)
constexpr int TBLOCKS = 2 * NP * BPN;   // 14336 transform blocks
constexpr long long DOF6_OFF = 2LL * NP * FPN;  // 44040192
typedef float v4 __attribute__((ext_vector_type(4)));
}

// Build R (row-major 3x3) and b = t + C - C@R for slice n.
// Matches reference: R = Rx@Ry@Rz; M = T(-C)@Rot(R)@T(t)@T(C); p' = p@R + b.
__device__ __forceinline__ void euler_Rb(const float* __restrict__ C,
                                         const float* __restrict__ ang,
                                         const float* __restrict__ t,
                                         int n, float R[9], float b[3]) {
    float ax = ang[n*3+0], ay = ang[n*3+1], az = ang[n*3+2];
    float cx = cosf(ax), sx = sinf(ax);
    float cy = cosf(ay), sy = sinf(ay);
    float cz = cosf(az), sz = sinf(az);
    float A00 = cy,       A01 = 0.f, A02 = sy;
    float A10 = sx*sy,    A11 = cx,  A12 = -sx*cy;
    float A20 = -cx*sy,   A21 = sx,  A22 = cx*cy;
    R[0] = A00*cz + A01*sz;  R[1] = -A00*sz + A01*cz;  R[2] = A02;
    R[3] = A10*cz + A11*sz;  R[4] = -A10*sz + A11*cz;  R[5] = A12;
    R[6] = A20*cz + A21*sz;  R[7] = -A20*sz + A21*cz;  R[8] = A22;
    float C0 = C[n*3+0], C1 = C[n*3+1], C2 = C[n*3+2];
    b[0] = t[n*3+0] + C0 - (C0*R[0] + C1*R[3] + C2*R[6]);
    b[1] = t[n*3+1] + C1 - (C0*R[1] + C1*R[4] + C2*R[7]);
    b[2] = t[n*3+2] + C2 - (C0*R[2] + C1*R[5] + C2*R[8]);
}

__global__ __launch_bounds__(256) void TrainDataAugmentation_kernel(
        const float* __restrict__ C,   const float* __restrict__ Xv,
        const float* __restrict__ tXv, const float* __restrict__ ang1,
        const float* __restrict__ ang2, const float* __restrict__ t1,
        const float* __restrict__ t2,  float* __restrict__ out) {
    int bid = blockIdx.x;
    if (bid < TBLOCKS) {
        __shared__ float s[12];
        __shared__ float st[4][768];           // per-wave 3072B staging
        const int tid = threadIdx.x;
        int arr = (bid >= NP * BPN) ? 1 : 0;
        int w   = bid - arr * (NP * BPN);
        int n   = w >> 8;
        int blk = w & 255;
        if (tid == 0) {
            float R[9], b[3];
            euler_Rb(C, arr ? ang2 : ang1, arr ? t2 : t1, n, R, b);
            #pragma unroll
            for (int i = 0; i < 9; ++i) s[i] = R[i];
            s[9] = b[0]; s[10] = b[1]; s[11] = b[2];
        }
        __syncthreads();
        const float R00=s[0],R01=s[1],R02=s[2],R10=s[3],R11=s[4],R12=s[5],
                    R20=s[6],R21=s[7],R22=s[8],b0=s[9],b1=s[10],b2=s[11];
        const float* __restrict__ in = arr ? tXv : Xv;
        float* __restrict__ o = out + (long long)arr * (long long)NP * FPN;
        const int wid = tid >> 6, L = tid & 63;
        float* __restrict__ W = &st[wid][0];
        long long wbase = (long long)n * FPN + (long long)blk * CHUNK_F + wid * 768;
        // ---- contiguous global loads: each wave instr covers 1024B ----
        v4 g0 = *(const v4*)(in + wbase + L*4);
        v4 g1 = *(const v4*)(in + wbase + 256 + L*4);
        v4 g2 = *(const v4*)(in + wbase + 512 + L*4);
        *(v4*)(W + L*4)       = g0;
        *(v4*)(W + 256 + L*4) = g1;
        *(v4*)(W + 512 + L*4) = g2;
        __syncthreads();
        // ---- point-aligned LDS reads: bank pattern 12L%32, conflict-free ----
        v4 v0 = *(const v4*)(W + L*12);
        v4 v1 = *(const v4*)(W + L*12 + 4);
        v4 v2 = *(const v4*)(W + L*12 + 8);
        v4 r0, r1, r2;
        float px, py, pz;
        px=v0.x; py=v0.y; pz=v0.z;
        r0.x = fmaf(px,R00,fmaf(py,R10,fmaf(pz,R20,b0)));
        r0.y = fmaf(px,R01,fmaf(py,R11,fmaf(pz,R21,b1)));
        r0.z = fmaf(px,R02,fmaf(py,R12,fmaf(pz,R22,b2)));
        px=v0.w; py=v1.x; pz=v1.y;
        r0.w = fmaf(px,R00,fmaf(py,R10,fmaf(pz,R20,b0)));
        r1.x = fmaf(px,R01,fmaf(py,R11,fmaf(pz,R21,b1)));
        r1.y = fmaf(px,R02,fmaf(py,R12,fmaf(pz,R22,b2)));
        px=v1.z; py=v1.w; pz=v2.x;
        r1.z = fmaf(px,R00,fmaf(py,R10,fmaf(pz,R20,b0)));
        r1.w = fmaf(px,R01,fmaf(py,R11,fmaf(pz,R21,b1)));
        r2.x = fmaf(px,R02,fmaf(py,R12,fmaf(pz,R22,b2)));
        px=v2.y; py=v2.z; pz=v2.w;
        r2.y = fmaf(px,R00,fmaf(py,R10,fmaf(pz,R20,b0)));
        r2.z = fmaf(px,R01,fmaf(py,R11,fmaf(pz,R21,b1)));
        r2.w = fmaf(px,R02,fmaf(py,R12,fmaf(pz,R22,b2)));
        // ---- point-aligned LDS writes (same wave, same addrs) ----
        *(v4*)(W + L*12)     = r0;
        *(v4*)(W + L*12 + 4) = r1;
        *(v4*)(W + L*12 + 8) = r2;
        __syncthreads();
        // ---- contiguous LDS reads -> contiguous global stores ----
        v4 s0 = *(const v4*)(W + L*4);
        v4 s1 = *(const v4*)(W + 256 + L*4);
        v4 s2 = *(const v4*)(W + 512 + L*4);
        *(v4*)(o + wbase + L*4)       = s0;
        *(v4*)(o + wbase + 256 + L*4) = s1;
        *(v4*)(o + wbase + 512 + L*4) = s2;
    } else {
        // dof6 block: 28 threads, one per n
        int n = threadIdx.x;
        if (n >= NP) return;
        float R1[9], b1v[3], R2[9], b2v[3];
        euler_Rb(C, ang1, t1, n, R1, b1v);
        euler_Rb(C, ang2, t2, n, R2, b2v);
        float Rf[9];
        #pragma unroll
        for (int i = 0; i < 3; ++i)
            #pragma unroll
            for (int j = 0; j < 3; ++j)
                Rf[3*i+j] = R1[0+i]*R2[0+j] + R1[3+i]*R2[3+j] + R1[6+i]*R2[6+j];
        float tf0 = b2v[0] - (b1v[0]*Rf[0] + b1v[1]*Rf[3] + b1v[2]*Rf[6]);
        float tf1 = b2v[1] - (b1v[0]*Rf[1] + b1v[1]*Rf[4] + b1v[2]*Rf[7]);
        float tf2 = b2v[2] - (b1v[0]*Rf[2] + b1v[1]*Rf[5] + b1v[2]*Rf[8]);
        const float eps = 1e-4f, cos_bound = 1e-4f;
        float tr = Rf[0] + Rf[4] + Rf[8];
        float cc = (tr - 1.f) * 0.5f;
        cc = fminf(fmaxf(cc, -1.f + cos_bound), 1.f - cos_bound);
        float phi = acosf(cc);
        float sp  = sinf(phi);
        float fac = (fabsf(sp) > 0.5f * eps) ? (phi / (2.f * sp))
                                             : (0.5f + phi * phi * (1.f/12.f));
        float w0 = fac * (Rf[7] - Rf[5]);
        float w1 = fac * (Rf[2] - Rf[6]);
        float w2 = fac * (Rf[3] - Rf[1]);
        float ww  = w0*w0 + w1*w1 + w2*w2;
        float th2 = fmaxf(ww, eps);
        float th  = sqrtf(th2);
        float a  = (1.f - cosf(th)) / th2;
        float bb = (th - sinf(th)) / (th2 * th);
        float V00 = 1.f + bb*(w0*w0 - ww);
        float V01 = -a*w2 + bb*w0*w1;
        float V02 =  a*w1 + bb*w0*w2;
        float V10 =  a*w2 + bb*w0*w1;
        float V11 = 1.f + bb*(w1*w1 - ww);
        float V12 = -a*w0 + bb*w1*w2;
        float V20 = -a*w1 + bb*w0*w2;
        float V21 =  a*w0 + bb*w1*w2;
        float V22 = 1.f + bb*(w2*w2 - ww);
        float a00 = V11*V22 - V12*V21;
        float a01 = V02*V21 - V01*V22;
        float a02 = V01*V12 - V02*V11;
        float a10 = V12*V20 - V10*V22;
        float a11 = V00*V22 - V02*V20;
        float a12 = V02*V10 - V00*V12;
        float a20 = V10*V21 - V11*V20;
        float a21 = V01*V20 - V00*V21;
        float a22 = V00*V11 - V01*V10;
        float det = V00*a00 + V01*a10 + V02*a20;
        float inv = 1.f / det;
        float x0 = (a00*tf0 + a01*tf1 + a02*tf2) * inv;
        float x1 = (a10*tf0 + a11*tf1 + a12*tf2) * inv;
        float x2 = (a20*tf0 + a21*tf1 + a22*tf2) * inv;
        float* d = out + DOF6_OFF + (long long)n * 6;
        d[0] = x0; d[1] = x1; d[2] = x2;
        d[3] = w0; d[4] = w1; d[5] = w2;
    }
}

extern "C" void kernel_launch(void* const* d_in, const int* in_sizes, int n_in,
                              void* d_out, int out_size, void* d_ws, size_t ws_size,
                              hipStream_t stream) {
    const float* C   = (const float*)d_in[0];
    const float* Xv  = (const float*)d_in[1];
    const float* tXv = (const float*)d_in[2];
    const float* a1  = (const float*)d_in[3];
    const float* a2  = (const float*)d_in[4];
    const float* t1  = (const float*)d_in[5];
    const float* t2  = (const float*)d_in[6];
    TrainDataAugmentation_kernel<<<TBLOCKS + 1, 256, 0, stream>>>(
        C, Xv, tXv, a1, a2, t1, t2, (float*)d_out);
}

// Round 4
// 66.775 us; speedup vs baseline: 1.4555x; 1.0008x over previous
//
#include <hip/hip_runtime.h>

namespace {
constexpr int NP  = 28;
constexpr int PTS = 262144;
constexpr int FPN = PTS * 3;              // floats per n-slice = 786432
constexpr int PPB = 1024;                 // points per block (256 thr * 4)
constexpr int BPN = PTS / PPB;            // 256 blocks per (array,n)
constexpr int TBLOCKS = 2 * NP * BPN;     // 14336 transform blocks
constexpr long long DOF6_OFF = 2LL * NP * FPN;  // 44040192
typedef float v3 __attribute__((ext_vector_type(3)));
}

// Build R (row-major 3x3) and b = t + C - C@R for slice n.
// Matches reference: R = Rx@Ry@Rz; M = T(-C)@Rot(R)@T(t)@T(C); p' = p@R + b.
__device__ __forceinline__ void euler_Rb(const float* __restrict__ C,
                                         const float* __restrict__ ang,
                                         const float* __restrict__ t,
                                         int n, float R[9], float b[3]) {
    float ax = ang[n*3+0], ay = ang[n*3+1], az = ang[n*3+2];
    float cx = cosf(ax), sx = sinf(ax);
    float cy = cosf(ay), sy = sinf(ay);
    float cz = cosf(az), sz = sinf(az);
    float A00 = cy,       A01 = 0.f, A02 = sy;
    float A10 = sx*sy,    A11 = cx,  A12 = -sx*cy;
    float A20 = -cx*sy,   A21 = sx,  A22 = cx*cy;
    R[0] = A00*cz + A01*sz;  R[1] = -A00*sz + A01*cz;  R[2] = A02;
    R[3] = A10*cz + A11*sz;  R[4] = -A10*sz + A11*cz;  R[5] = A12;
    R[6] = A20*cz + A21*sz;  R[7] = -A20*sz + A21*cz;  R[8] = A22;
    float C0 = C[n*3+0], C1 = C[n*3+1], C2 = C[n*3+2];
    b[0] = t[n*3+0] + C0 - (C0*R[0] + C1*R[3] + C2*R[6]);
    b[1] = t[n*3+1] + C1 - (C0*R[1] + C1*R[4] + C2*R[7]);
    b[2] = t[n*3+2] + C2 - (C0*R[2] + C1*R[5] + C2*R[8]);
}

__global__ __launch_bounds__(256) void TrainDataAugmentation_kernel(
        const float* __restrict__ C,   const float* __restrict__ Xv,
        const float* __restrict__ tXv, const float* __restrict__ ang1,
        const float* __restrict__ ang2, const float* __restrict__ t1,
        const float* __restrict__ t2,  float* __restrict__ out) {
    int bid = blockIdx.x;
    if (bid < TBLOCKS) {
        const int tid = threadIdx.x;
        int arr = (bid >= NP * BPN) ? 1 : 0;
        int w   = bid - arr * (NP * BPN);
        int n   = w >> 8;
        int blk = w & 255;
        const float* __restrict__ in = arr ? tXv : Xv;
        float* __restrict__ o = out + (long long)arr * (long long)NP * FPN;
        // point index: wave wid owns [wid*256, wid*256+256); lane L takes L + s*64.
        const int wid = tid >> 6, L = tid & 63;
        long long p0 = (long long)n * PTS + (long long)blk * PPB + wid * 256 + L;
        // ---- issue all 4 fully-contiguous dwordx3 loads first ----
        v3 q0 = *(const v3*)(in + 3 * p0);
        v3 q1 = *(const v3*)(in + 3 * (p0 + 64));
        v3 q2 = *(const v3*)(in + 3 * (p0 + 128));
        v3 q3 = *(const v3*)(in + 3 * (p0 + 192));
        // ---- matrix math hides under VMEM latency (no LDS, no barrier) ----
        float R[9], b[3];
        euler_Rb(C, arr ? ang2 : ang1, arr ? t2 : t1, n, R, b);
        v3 r0, r1, r2, r3;
        r0.x = fmaf(q0.x,R[0],fmaf(q0.y,R[3],fmaf(q0.z,R[6],b[0])));
        r0.y = fmaf(q0.x,R[1],fmaf(q0.y,R[4],fmaf(q0.z,R[7],b[1])));
        r0.z = fmaf(q0.x,R[2],fmaf(q0.y,R[5],fmaf(q0.z,R[8],b[2])));
        r1.x = fmaf(q1.x,R[0],fmaf(q1.y,R[3],fmaf(q1.z,R[6],b[0])));
        r1.y = fmaf(q1.x,R[1],fmaf(q1.y,R[4],fmaf(q1.z,R[7],b[1])));
        r1.z = fmaf(q1.x,R[2],fmaf(q1.y,R[5],fmaf(q1.z,R[8],b[2])));
        r2.x = fmaf(q2.x,R[0],fmaf(q2.y,R[3],fmaf(q2.z,R[6],b[0])));
        r2.y = fmaf(q2.x,R[1],fmaf(q2.y,R[4],fmaf(q2.z,R[7],b[1])));
        r2.z = fmaf(q2.x,R[2],fmaf(q2.y,R[5],fmaf(q2.z,R[8],b[2])));
        r3.x = fmaf(q3.x,R[0],fmaf(q3.y,R[3],fmaf(q3.z,R[6],b[0])));
        r3.y = fmaf(q3.x,R[1],fmaf(q3.y,R[4],fmaf(q3.z,R[7],b[1])));
        r3.z = fmaf(q3.x,R[2],fmaf(q3.y,R[5],fmaf(q3.z,R[8],b[2])));
        *(v3*)(o + 3 * p0)         = r0;
        *(v3*)(o + 3 * (p0 + 64))  = r1;
        *(v3*)(o + 3 * (p0 + 128)) = r2;
        *(v3*)(o + 3 * (p0 + 192)) = r3;
    } else {
        // dof6 block: 28 threads, one per n
        int n = threadIdx.x;
        if (n >= NP) return;
        float R1[9], b1v[3], R2[9], b2v[3];
        euler_Rb(C, ang1, t1, n, R1, b1v);
        euler_Rb(C, ang2, t2, n, R2, b2v);
        // Ffinal = inv(M1)@M2: Rf = R1^T @ R2, tf = b2 - b1@Rf
        float Rf[9];
        #pragma unroll
        for (int i = 0; i < 3; ++i)
            #pragma unroll
            for (int j = 0; j < 3; ++j)
                Rf[3*i+j] = R1[0+i]*R2[0+j] + R1[3+i]*R2[3+j] + R1[6+i]*R2[6+j];
        float tf0 = b2v[0] - (b1v[0]*Rf[0] + b1v[1]*Rf[3] + b1v[2]*Rf[6]);
        float tf1 = b2v[1] - (b1v[0]*Rf[1] + b1v[1]*Rf[4] + b1v[2]*Rf[7]);
        float tf2 = b2v[2] - (b1v[0]*Rf[2] + b1v[1]*Rf[5] + b1v[2]*Rf[8]);
        const float eps = 1e-4f, cos_bound = 1e-4f;
        float tr = Rf[0] + Rf[4] + Rf[8];
        float cc = (tr - 1.f) * 0.5f;
        cc = fminf(fmaxf(cc, -1.f + cos_bound), 1.f - cos_bound);
        float phi = acosf(cc);
        float sp  = sinf(phi);
        float fac = (fabsf(sp) > 0.5f * eps) ? (phi / (2.f * sp))
                                             : (0.5f + phi * phi * (1.f/12.f));
        float w0 = fac * (Rf[7] - Rf[5]);
        float w1 = fac * (Rf[2] - Rf[6]);
        float w2 = fac * (Rf[3] - Rf[1]);
        float ww  = w0*w0 + w1*w1 + w2*w2;
        float th2 = fmaxf(ww, eps);
        float th  = sqrtf(th2);
        float a  = (1.f - cosf(th)) / th2;
        float bb = (th - sinf(th)) / (th2 * th);
        float V00 = 1.f + bb*(w0*w0 - ww);
        float V01 = -a*w2 + bb*w0*w1;
        float V02 =  a*w1 + bb*w0*w2;
        float V10 =  a*w2 + bb*w0*w1;
        float V11 = 1.f + bb*(w1*w1 - ww);
        float V12 = -a*w0 + bb*w1*w2;
        float V20 = -a*w1 + bb*w0*w2;
        float V21 =  a*w0 + bb*w1*w2;
        float V22 = 1.f + bb*(w2*w2 - ww);
        float a00 = V11*V22 - V12*V21;
        float a01 = V02*V21 - V01*V22;
        float a02 = V01*V12 - V02*V11;
        float a10 = V12*V20 - V10*V22;
        float a11 = V00*V22 - V02*V20;
        float a12 = V02*V10 - V00*V12;
        float a20 = V10*V21 - V11*V20;
        float a21 = V01*V20 - V00*V21;
        float a22 = V00*V11 - V01*V10;
        float det = V00*a00 + V01*a10 + V02*a20;
        float inv = 1.f / det;
        float x0 = (a00*tf0 + a01*tf1 + a02*tf2) * inv;
        float x1 = (a10*tf0 + a11*tf1 + a12*tf2) * inv;
        float x2 = (a20*tf0 + a21*tf1 + a22*tf2) * inv;
        float* d = out + DOF6_OFF + (long long)n * 6;
        d[0] = x0; d[1] = x1; d[2] = x2;
        d[3] = w0; d[4] = w1; d[5] = w2;
    }
}

extern "C" void kernel_launch(void* const* d_in, const int* in_sizes, int n_in,
                              void* d_out, int out_size, void* d_ws, size_t ws_size,
                              hipStream_t stream) {
    const float* C   = (const float*)d_in[0];
    const float* Xv  = (const float*)d_in[1];
    const float* tXv = (const float*)d_in[2];
    const float* a1  = (const float*)d_in[3];
    const float* a2  = (const float*)d_in[4];
    const float* t1  = (const float*)d_in[5];
    const float* t2  = (const float*)d_in[6];
    TrainDataAugmentation_kernel<<<TBLOCKS + 1, 256, 0, stream>>>(
        C, Xv, tXv, a1, a2, t1, t2, (float*)d_out);
}

// Round 5
// 54.987 us; speedup vs baseline: 1.7675x; 1.2144x over previous
//
#include <hip/hip_runtime.h>

namespace {
constexpr int NP  = 28;
constexpr int PTS = 262144;
constexpr int FPN = PTS * 3;              // floats per n-slice = 786432
constexpr int PPB = 1024;                 // points per block (256 thr * 4)
constexpr int BPN = PTS / PPB;            // 256 blocks per (array,n)
constexpr int TBLOCKS = 2 * NP * BPN;     // 14336 transform blocks
constexpr long long DOF6_OFF = 2LL * NP * FPN;  // 44040192
typedef float v3 __attribute__((ext_vector_type(3)));
}

// Build R (row-major 3x3) and b = t + C - C@R for slice n.
// Matches reference: R = Rx@Ry@Rz; M = T(-C)@Rot(R)@T(t)@T(C); p' = p@R + b.
__device__ __forceinline__ void euler_Rb(const float* __restrict__ C,
                                         const float* __restrict__ ang,
                                         const float* __restrict__ t,
                                         int n, float R[9], float b[3]) {
    float ax = ang[n*3+0], ay = ang[n*3+1], az = ang[n*3+2];
    float cx = cosf(ax), sx = sinf(ax);
    float cy = cosf(ay), sy = sinf(ay);
    float cz = cosf(az), sz = sinf(az);
    float A00 = cy,       A01 = 0.f, A02 = sy;
    float A10 = sx*sy,    A11 = cx,  A12 = -sx*cy;
    float A20 = -cx*sy,   A21 = sx,  A22 = cx*cy;
    R[0] = A00*cz + A01*sz;  R[1] = -A00*sz + A01*cz;  R[2] = A02;
    R[3] = A10*cz + A11*sz;  R[4] = -A10*sz + A11*cz;  R[5] = A12;
    R[6] = A20*cz + A21*sz;  R[7] = -A20*sz + A21*cz;  R[8] = A22;
    float C0 = C[n*3+0], C1 = C[n*3+1], C2 = C[n*3+2];
    b[0] = t[n*3+0] + C0 - (C0*R[0] + C1*R[3] + C2*R[6]);
    b[1] = t[n*3+1] + C1 - (C0*R[1] + C1*R[4] + C2*R[7]);
    b[2] = t[n*3+2] + C2 - (C0*R[2] + C1*R[5] + C2*R[8]);
}

__global__ __launch_bounds__(256) void TrainDataAugmentation_kernel(
        const float* __restrict__ C,   const float* __restrict__ Xv,
        const float* __restrict__ tXv, const float* __restrict__ ang1,
        const float* __restrict__ ang2, const float* __restrict__ t1,
        const float* __restrict__ t2,  float* __restrict__ out) {
    int bid = blockIdx.x;
    if (bid < TBLOCKS) {
        const int tid = threadIdx.x;
        int arr = (bid >= NP * BPN) ? 1 : 0;
        int w   = bid - arr * (NP * BPN);
        int n   = w >> 8;
        int blk = w & 255;
        const float* __restrict__ in = arr ? tXv : Xv;
        float* __restrict__ o = out + (long long)arr * (long long)NP * FPN;
        // point index: wave wid owns [wid*256, wid*256+256); lane L takes L + s*64.
        const int wid = tid >> 6, L = tid & 63;
        long long p0 = (long long)n * PTS + (long long)blk * PPB + wid * 256 + L;
        // ---- issue all 4 fully-contiguous dwordx3 loads first ----
        v3 q0 = *(const v3*)(in + 3 * p0);
        v3 q1 = *(const v3*)(in + 3 * (p0 + 64));
        v3 q2 = *(const v3*)(in + 3 * (p0 + 128));
        v3 q3 = *(const v3*)(in + 3 * (p0 + 192));
        // ---- matrix math hides under VMEM latency (no LDS, no barrier) ----
        float R[9], b[3];
        euler_Rb(C, arr ? ang2 : ang1, arr ? t2 : t1, n, R, b);
        v3 r0, r1, r2, r3;
        r0.x = fmaf(q0.x,R[0],fmaf(q0.y,R[3],fmaf(q0.z,R[6],b[0])));
        r0.y = fmaf(q0.x,R[1],fmaf(q0.y,R[4],fmaf(q0.z,R[7],b[1])));
        r0.z = fmaf(q0.x,R[2],fmaf(q0.y,R[5],fmaf(q0.z,R[8],b[2])));
        r1.x = fmaf(q1.x,R[0],fmaf(q1.y,R[3],fmaf(q1.z,R[6],b[0])));
        r1.y = fmaf(q1.x,R[1],fmaf(q1.y,R[4],fmaf(q1.z,R[7],b[1])));
        r1.z = fmaf(q1.x,R[2],fmaf(q1.y,R[5],fmaf(q1.z,R[8],b[2])));
        r2.x = fmaf(q2.x,R[0],fmaf(q2.y,R[3],fmaf(q2.z,R[6],b[0])));
        r2.y = fmaf(q2.x,R[1],fmaf(q2.y,R[4],fmaf(q2.z,R[7],b[1])));
        r2.z = fmaf(q2.x,R[2],fmaf(q2.y,R[5],fmaf(q2.z,R[8],b[2])));
        r3.x = fmaf(q3.x,R[0],fmaf(q3.y,R[3],fmaf(q3.z,R[6],b[0])));
        r3.y = fmaf(q3.x,R[1],fmaf(q3.y,R[4],fmaf(q3.z,R[7],b[1])));
        r3.z = fmaf(q3.x,R[2],fmaf(q3.y,R[5],fmaf(q3.z,R[8],b[2])));
        // ---- nontemporal stores: don't displace the (L3-resident) input ----
        __builtin_nontemporal_store(r0, (v3*)(o + 3 * p0));
        __builtin_nontemporal_store(r1, (v3*)(o + 3 * (p0 + 64)));
        __builtin_nontemporal_store(r2, (v3*)(o + 3 * (p0 + 128)));
        __builtin_nontemporal_store(r3, (v3*)(o + 3 * (p0 + 192)));
    } else {
        // dof6 block: 28 threads, one per n
        int n = threadIdx.x;
        if (n >= NP) return;
        float R1[9], b1v[3], R2[9], b2v[3];
        euler_Rb(C, ang1, t1, n, R1, b1v);
        euler_Rb(C, ang2, t2, n, R2, b2v);
        // Ffinal = inv(M1)@M2: Rf = R1^T @ R2, tf = b2 - b1@Rf
        float Rf[9];
        #pragma unroll
        for (int i = 0; i < 3; ++i)
            #pragma unroll
            for (int j = 0; j < 3; ++j)
                Rf[3*i+j] = R1[0+i]*R2[0+j] + R1[3+i]*R2[3+j] + R1[6+i]*R2[6+j];
        float tf0 = b2v[0] - (b1v[0]*Rf[0] + b1v[1]*Rf[3] + b1v[2]*Rf[6]);
        float tf1 = b2v[1] - (b1v[0]*Rf[1] + b1v[1]*Rf[4] + b1v[2]*Rf[7]);
        float tf2 = b2v[2] - (b1v[0]*Rf[2] + b1v[1]*Rf[5] + b1v[2]*Rf[8]);
        const float eps = 1e-4f, cos_bound = 1e-4f;
        float tr = Rf[0] + Rf[4] + Rf[8];
        float cc = (tr - 1.f) * 0.5f;
        cc = fminf(fmaxf(cc, -1.f + cos_bound), 1.f - cos_bound);
        float phi = acosf(cc);
        float sp  = sinf(phi);
        float fac = (fabsf(sp) > 0.5f * eps) ? (phi / (2.f * sp))
                                             : (0.5f + phi * phi * (1.f/12.f));
        float w0 = fac * (Rf[7] - Rf[5]);
        float w1 = fac * (Rf[2] - Rf[6]);
        float w2 = fac * (Rf[3] - Rf[1]);
        float ww  = w0*w0 + w1*w1 + w2*w2;
        float th2 = fmaxf(ww, eps);
        float th  = sqrtf(th2);
        float a  = (1.f - cosf(th)) / th2;
        float bb = (th - sinf(th)) / (th2 * th);
        float V00 = 1.f + bb*(w0*w0 - ww);
        float V01 = -a*w2 + bb*w0*w1;
        float V02 =  a*w1 + bb*w0*w2;
        float V10 =  a*w2 + bb*w0*w1;
        float V11 = 1.f + bb*(w1*w1 - ww);
        float V12 = -a*w0 + bb*w1*w2;
        float V20 = -a*w1 + bb*w0*w2;
        float V21 =  a*w0 + bb*w1*w2;
        float V22 = 1.f + bb*(w2*w2 - ww);
        float a00 = V11*V22 - V12*V21;
        float a01 = V02*V21 - V01*V22;
        float a02 = V01*V12 - V02*V11;
        float a10 = V12*V20 - V10*V22;
        float a11 = V00*V22 - V02*V20;
        float a12 = V02*V10 - V00*V12;
        float a20 = V10*V21 - V11*V20;
        float a21 = V01*V20 - V00*V21;
        float a22 = V00*V11 - V01*V10;
        float det = V00*a00 + V01*a10 + V02*a20;
        float inv = 1.f / det;
        float x0 = (a00*tf0 + a01*tf1 + a02*tf2) * inv;
        float x1 = (a10*tf0 + a11*tf1 + a12*tf2) * inv;
        float x2 = (a20*tf0 + a21*tf1 + a22*tf2) * inv;
        float* d = out + DOF6_OFF + (long long)n * 6;
        d[0] = x0; d[1] = x1; d[2] = x2;
        d[3] = w0; d[4] = w1; d[5] = w2;
    }
}

extern "C" void kernel_launch(void* const* d_in, const int* in_sizes, int n_in,
                              void* d_out, int out_size, void* d_ws, size_t ws_size,
                              hipStream_t stream) {
    const float* C   = (const float*)d_in[0];
    const float* Xv  = (const float*)d_in[1];
    const float* tXv = (const float*)d_in[2];
    const float* a1  = (const float*)d_in[3];
    const float* a2  = (const float*)d_in[4];
    const float* t1  = (const float*)d_in[5];
    const float* t2  = (const float*)d_in[6];
    TrainDataAugmentation_kernel<<<TBLOCKS + 1, 256, 0, stream>>>(
        C, Xv, tXv, a1, a2, t1, t2, (float*)d_out);
}

// Round 6
// 54.501 us; speedup vs baseline: 1.7833x; 1.0089x over previous
//
#include <hip/hip_runtime.h>

namespace {
constexpr int NP  = 28;
constexpr int PTS = 262144;
constexpr int FPN = PTS * 3;              // floats per n-slice = 786432
constexpr int PPB = 1024;                 // points per block (256 thr * 4)
constexpr int BPN = PTS / PPB;            // 256 blocks per (array,n)
constexpr int TBLOCKS = 2 * NP * BPN;     // 14336 transform blocks
constexpr long long DOF6_OFF = 2LL * NP * FPN;  // 44040192
typedef float v3 __attribute__((ext_vector_type(3)));
}

// Streaming store: nt (non-temporal) + sc0 sc1 (system-scope write-through)
// => no L2/L3 line allocation; keeps the 176MB input L3-resident.
__device__ __forceinline__ void store_nt3(float* p, v3 v) {
    asm volatile("global_store_dwordx3 %0, %1, off nt sc0 sc1"
                 :: "v"(p), "v"(v) : "memory");
}

// Build R (row-major 3x3) and b = t + C - C@R for slice n.
// Matches reference: R = Rx@Ry@Rz; M = T(-C)@Rot(R)@T(t)@T(C); p' = p@R + b.
__device__ __forceinline__ void euler_Rb(const float* __restrict__ C,
                                         const float* __restrict__ ang,
                                         const float* __restrict__ t,
                                         int n, float R[9], float b[3]) {
    float ax = ang[n*3+0], ay = ang[n*3+1], az = ang[n*3+2];
    float cx = cosf(ax), sx = sinf(ax);
    float cy = cosf(ay), sy = sinf(ay);
    float cz = cosf(az), sz = sinf(az);
    float A00 = cy,       A01 = 0.f, A02 = sy;
    float A10 = sx*sy,    A11 = cx,  A12 = -sx*cy;
    float A20 = -cx*sy,   A21 = sx,  A22 = cx*cy;
    R[0] = A00*cz + A01*sz;  R[1] = -A00*sz + A01*cz;  R[2] = A02;
    R[3] = A10*cz + A11*sz;  R[4] = -A10*sz + A11*cz;  R[5] = A12;
    R[6] = A20*cz + A21*sz;  R[7] = -A20*sz + A21*cz;  R[8] = A22;
    float C0 = C[n*3+0], C1 = C[n*3+1], C2 = C[n*3+2];
    b[0] = t[n*3+0] + C0 - (C0*R[0] + C1*R[3] + C2*R[6]);
    b[1] = t[n*3+1] + C1 - (C0*R[1] + C1*R[4] + C2*R[7]);
    b[2] = t[n*3+2] + C2 - (C0*R[2] + C1*R[5] + C2*R[8]);
}

__global__ __launch_bounds__(256) void TrainDataAugmentation_kernel(
        const float* __restrict__ C,   const float* __restrict__ Xv,
        const float* __restrict__ tXv, const float* __restrict__ ang1,
        const float* __restrict__ ang2, const float* __restrict__ t1,
        const float* __restrict__ t2,  float* __restrict__ out) {
    int bid = blockIdx.x;
    if (bid < TBLOCKS) {
        const int tid = threadIdx.x;
        int arr = (bid >= NP * BPN) ? 1 : 0;
        int w   = bid - arr * (NP * BPN);
        int n   = w >> 8;
        int blk = w & 255;
        const float* __restrict__ in = arr ? tXv : Xv;
        float* __restrict__ o = out + (long long)arr * (long long)NP * FPN;
        // point index: wave wid owns [wid*256, wid*256+256); lane L takes L + s*64.
        const int wid = tid >> 6, L = tid & 63;
        long long p0 = (long long)n * PTS + (long long)blk * PPB + wid * 256 + L;
        // ---- issue all 4 fully-contiguous dwordx3 loads first (cached) ----
        v3 q0 = *(const v3*)(in + 3 * p0);
        v3 q1 = *(const v3*)(in + 3 * (p0 + 64));
        v3 q2 = *(const v3*)(in + 3 * (p0 + 128));
        v3 q3 = *(const v3*)(in + 3 * (p0 + 192));
        // ---- matrix math hides under VMEM latency (no LDS, no barrier) ----
        float R[9], b[3];
        euler_Rb(C, arr ? ang2 : ang1, arr ? t2 : t1, n, R, b);
        v3 r0, r1, r2, r3;
        r0.x = fmaf(q0.x,R[0],fmaf(q0.y,R[3],fmaf(q0.z,R[6],b[0])));
        r0.y = fmaf(q0.x,R[1],fmaf(q0.y,R[4],fmaf(q0.z,R[7],b[1])));
        r0.z = fmaf(q0.x,R[2],fmaf(q0.y,R[5],fmaf(q0.z,R[8],b[2])));
        r1.x = fmaf(q1.x,R[0],fmaf(q1.y,R[3],fmaf(q1.z,R[6],b[0])));
        r1.y = fmaf(q1.x,R[1],fmaf(q1.y,R[4],fmaf(q1.z,R[7],b[1])));
        r1.z = fmaf(q1.x,R[2],fmaf(q1.y,R[5],fmaf(q1.z,R[8],b[2])));
        r2.x = fmaf(q2.x,R[0],fmaf(q2.y,R[3],fmaf(q2.z,R[6],b[0])));
        r2.y = fmaf(q2.x,R[1],fmaf(q2.y,R[4],fmaf(q2.z,R[7],b[1])));
        r2.z = fmaf(q2.x,R[2],fmaf(q2.y,R[5],fmaf(q2.z,R[8],b[2])));
        r3.x = fmaf(q3.x,R[0],fmaf(q3.y,R[3],fmaf(q3.z,R[6],b[0])));
        r3.y = fmaf(q3.x,R[1],fmaf(q3.y,R[4],fmaf(q3.z,R[7],b[1])));
        r3.z = fmaf(q3.x,R[2],fmaf(q3.y,R[5],fmaf(q3.z,R[8],b[2])));
        // ---- streaming stores: zero cache allocation on the write path ----
        store_nt3(o + 3 * p0,         r0);
        store_nt3(o + 3 * (p0 + 64),  r1);
        store_nt3(o + 3 * (p0 + 128), r2);
        store_nt3(o + 3 * (p0 + 192), r3);
    } else {
        // dof6 block: 28 threads, one per n
        int n = threadIdx.x;
        if (n >= NP) return;
        float R1[9], b1v[3], R2[9], b2v[3];
        euler_Rb(C, ang1, t1, n, R1, b1v);
        euler_Rb(C, ang2, t2, n, R2, b2v);
        // Ffinal = inv(M1)@M2: Rf = R1^T @ R2, tf = b2 - b1@Rf
        float Rf[9];
        #pragma unroll
        for (int i = 0; i < 3; ++i)
            #pragma unroll
            for (int j = 0; j < 3; ++j)
                Rf[3*i+j] = R1[0+i]*R2[0+j] + R1[3+i]*R2[3+j] + R1[6+i]*R2[6+j];
        float tf0 = b2v[0] - (b1v[0]*Rf[0] + b1v[1]*Rf[3] + b1v[2]*Rf[6]);
        float tf1 = b2v[1] - (b1v[0]*Rf[1] + b1v[1]*Rf[4] + b1v[2]*Rf[7]);
        float tf2 = b2v[2] - (b1v[0]*Rf[2] + b1v[1]*Rf[5] + b1v[2]*Rf[8]);
        const float eps = 1e-4f, cos_bound = 1e-4f;
        float tr = Rf[0] + Rf[4] + Rf[8];
        float cc = (tr - 1.f) * 0.5f;
        cc = fminf(fmaxf(cc, -1.f + cos_bound), 1.f - cos_bound);
        float phi = acosf(cc);
        float sp  = sinf(phi);
        float fac = (fabsf(sp) > 0.5f * eps) ? (phi / (2.f * sp))
                                             : (0.5f + phi * phi * (1.f/12.f));
        float w0 = fac * (Rf[7] - Rf[5]);
        float w1 = fac * (Rf[2] - Rf[6]);
        float w2 = fac * (Rf[3] - Rf[1]);
        float ww  = w0*w0 + w1*w1 + w2*w2;
        float th2 = fmaxf(ww, eps);
        float th  = sqrtf(th2);
        float a  = (1.f - cosf(th)) / th2;
        float bb = (th - sinf(th)) / (th2 * th);
        float V00 = 1.f + bb*(w0*w0 - ww);
        float V01 = -a*w2 + bb*w0*w1;
        float V02 =  a*w1 + bb*w0*w2;
        float V10 =  a*w2 + bb*w0*w1;
        float V11 = 1.f + bb*(w1*w1 - ww);
        float V12 = -a*w0 + bb*w1*w2;
        float V20 = -a*w1 + bb*w0*w2;
        float V21 =  a*w0 + bb*w1*w2;
        float V22 = 1.f + bb*(w2*w2 - ww);
        float a00 = V11*V22 - V12*V21;
        float a01 = V02*V21 - V01*V22;
        float a02 = V01*V12 - V02*V11;
        float a10 = V12*V20 - V10*V22;
        float a11 = V00*V22 - V02*V20;
        float a12 = V02*V10 - V00*V12;
        float a20 = V10*V21 - V11*V20;
        float a21 = V01*V20 - V00*V21;
        float a22 = V00*V11 - V01*V10;
        float det = V00*a00 + V01*a10 + V02*a20;
        float inv = 1.f / det;
        float x0 = (a00*tf0 + a01*tf1 + a02*tf2) * inv;
        float x1 = (a10*tf0 + a11*tf1 + a12*tf2) * inv;
        float x2 = (a20*tf0 + a21*tf1 + a22*tf2) * inv;
        float* d = out + DOF6_OFF + (long long)n * 6;
        d[0] = x0; d[1] = x1; d[2] = x2;
        d[3] = w0; d[4] = w1; d[5] = w2;
    }
}

extern "C" void kernel_launch(void* const* d_in, const int* in_sizes, int n_in,
                              void* d_out, int out_size, void* d_ws, size_t ws_size,
                              hipStream_t stream) {
    const float* C   = (const float*)d_in[0];
    const float* Xv  = (const float*)d_in[1];
    const float* tXv = (const float*)d_in[2];
    const float* a1  = (const float*)d_in[3];
    const float* a2  = (const float*)d_in[4];
    const float* t1  = (const float*)d_in[5];
    const float* t2  = (const float*)d_in[6];
    TrainDataAugmentation_kernel<<<TBLOCKS + 1, 256, 0, stream>>>(
        C, Xv, tXv, a1, a2, t1, t2, (float*)d_out);
}